// Round 1
// baseline (612.873 us; speedup 1.0000x reference)
//
#include <hip/hip_runtime.h>

// Problem constants
#define BB 32
#define SS 512
#define DD 768
#define HH 12
#define HDIM 64
#define OL 256        // pooled query length
#define NQKV 2304     // 3*DD
#define GM (BB*SS)    // 16384 rows into the QKV GEMM

typedef __bf16 bf16_t;
typedef bf16_t bf16x8 __attribute__((ext_vector_type(8)));
typedef float f32x4 __attribute__((ext_vector_type(4)));

__device__ __forceinline__ unsigned short f2bf(float f) {
  unsigned u = __float_as_uint(f);
  u = u + 0x7FFFu + ((u >> 16) & 1u);   // RNE
  return (unsigned short)(u >> 16);
}
__device__ __forceinline__ float b2f(unsigned short s) {
  return __uint_as_float(((unsigned)s) << 16);
}

// ---------------------------------------------------------------- conversions
__global__ void conv_f32_bf16(const float* __restrict__ in,
                              unsigned short* __restrict__ out, int n4) {
  int i = blockIdx.x * blockDim.x + threadIdx.x;
  if (i >= n4) return;
  float4 v = ((const float4*)in)[i];
  ushort4 o;
  o.x = f2bf(v.x); o.y = f2bf(v.y); o.z = f2bf(v.z); o.w = f2bf(v.w);
  ((ushort4*)out)[i] = o;
}

// ---------------------------------------------------------------- mask prep
// Robust to attention_mask arriving as uint8 bool, int32, or float32:
// lengths >= 128 so mask[1] is always true; for uint8 byte[1]==1, for
// int32/float32 byte[1]==0 (value 1 / 1.0f have zero in byte 1).
__global__ void prep_mask(const void* __restrict__ mraw,
                          float* __restrict__ kbias,
                          float* __restrict__ invn,
                          unsigned char* __restrict__ nmask,
                          float* __restrict__ out_nm) {
  int b = blockIdx.x, t = threadIdx.x;
  const unsigned char* mb = (const unsigned char*)mraw;
  bool isbyte = (mb[1] != 0);
  int idx = b * SS + t;
  int mv = isbyte ? (int)(mb[idx] != 0) : (int)(((const int*)mraw)[idx] != 0);
  kbias[idx] = mv ? 0.f : -10000.f;
  if (t < OL) {
    int i0 = b * SS + 2 * t, i1 = i0 + 1;
    int m0 = isbyte ? (int)(mb[i0] != 0) : (int)(((const int*)mraw)[i0] != 0);
    int m1 = isbyte ? (int)(mb[i1] != 0) : (int)(((const int*)mraw)[i1] != 0);
    int n = m0 + m1;
    invn[b * OL + t] = (n > 0) ? 1.f / (float)n : 1.f;
    nmask[b * OL + t] = (n > 0) ? 1 : 0;
    out_nm[b * OL + t] = (n > 0) ? 1.f : 0.f;   // second tuple output
  }
}

// ---------------------------------------------------------------- QKV GEMM
// C[m][n] = sum_k A[m][k] * W[n][k] + bias[n];  A,W bf16, C bf16.
// 128x128 tile, BK=32, 4 waves of 2x2, 4x4 16x16x32 MFMA frags per wave.
__global__ __launch_bounds__(256) void gemm_qkv(const unsigned short* __restrict__ A,
                                                const unsigned short* __restrict__ Bt,
                                                const float* __restrict__ bias,
                                                unsigned short* __restrict__ C) {
  __shared__ unsigned short sA[128 * 32];
  __shared__ unsigned short sB[128 * 32];
  const int t = threadIdx.x;
  const int lane = t & 63;
  const int w = t >> 6;
  const int wr = w >> 1, wc = w & 1;
  const int m0 = blockIdx.y * 128, n0 = blockIdx.x * 128;

  f32x4 acc[4][4] = {};

  const int r = t >> 2, cs = t & 3;       // staging: 64 rows x 4x16B per issue
  const unsigned short* ga0 = A + (size_t)(m0 + r) * DD + cs * 8;
  const unsigned short* ga1 = ga0 + (size_t)64 * DD;
  const unsigned short* gb0 = Bt + (size_t)(n0 + r) * DD + cs * 8;
  const unsigned short* gb1 = gb0 + (size_t)64 * DD;
  const int wvb = __builtin_amdgcn_readfirstlane(w << 10);  // wave LDS byte base
  char* sAb = (char*)sA;
  char* sBb = (char*)sB;

  const int fr = lane & 15;
  const int kk = (lane >> 4) * 8;

  for (int kt = 0; kt < DD; kt += 32) {
    __builtin_amdgcn_global_load_lds(
        (const __attribute__((address_space(1))) unsigned int*)(ga0 + kt),
        (__attribute__((address_space(3))) unsigned int*)(sAb + wvb), 16, 0, 0);
    __builtin_amdgcn_global_load_lds(
        (const __attribute__((address_space(1))) unsigned int*)(ga1 + kt),
        (__attribute__((address_space(3))) unsigned int*)(sAb + 4096 + wvb), 16, 0, 0);
    __builtin_amdgcn_global_load_lds(
        (const __attribute__((address_space(1))) unsigned int*)(gb0 + kt),
        (__attribute__((address_space(3))) unsigned int*)(sBb + wvb), 16, 0, 0);
    __builtin_amdgcn_global_load_lds(
        (const __attribute__((address_space(1))) unsigned int*)(gb1 + kt),
        (__attribute__((address_space(3))) unsigned int*)(sBb + 4096 + wvb), 16, 0, 0);
    __syncthreads();

    bf16x8 av[4], bv[4];
#pragma unroll
    for (int m = 0; m < 4; ++m)
      av[m] = *(const bf16x8*)(sA + (wr * 64 + m * 16 + fr) * 32 + kk);
#pragma unroll
    for (int n = 0; n < 4; ++n)
      bv[n] = *(const bf16x8*)(sB + (wc * 64 + n * 16 + fr) * 32 + kk);
#pragma unroll
    for (int m = 0; m < 4; ++m)
#pragma unroll
      for (int n = 0; n < 4; ++n)
        acc[m][n] = __builtin_amdgcn_mfma_f32_16x16x32_bf16(av[m], bv[n], acc[m][n], 0, 0, 0);
    __syncthreads();
  }

#pragma unroll
  for (int m = 0; m < 4; ++m) {
#pragma unroll
    for (int n = 0; n < 4; ++n) {
      const int gm = m0 + wr * 64 + m * 16 + (lane >> 4) * 4;  // C/D: row=(lane>>4)*4+j
      const int gn = n0 + wc * 64 + n * 16 + fr;               //      col=lane&15
      const float bvs = bias[gn];
#pragma unroll
      for (int j = 0; j < 4; ++j)
        C[(size_t)(gm + j) * NQKV + gn] = f2bf(acc[m][n][j] + bvs);
    }
  }
}

// ---------------------------------------------------------------- Q pooling
// q_pool[b][o][c] = (q[2o][c]*m(2o) + q[2o+1][c]*m(2o+1)) * invn[b][o]
__global__ void pool_q(const unsigned short* __restrict__ qkv,
                       const float* __restrict__ kbias,
                       const float* __restrict__ invn,
                       unsigned short* __restrict__ qp) {
  int i = blockIdx.x * blockDim.x + threadIdx.x;
  if (i >= (BB * OL * DD) / 4) return;
  int c = (i * 4) % DD;
  int ol = (i * 4) / DD;    // b*OL + o
  int b = ol >> 8, o = ol & 255;
  int s0 = b * SS + 2 * o;
  float m0 = (kbias[s0] == 0.f) ? 1.f : 0.f;
  float m1 = (kbias[s0 + 1] == 0.f) ? 1.f : 0.f;
  float inv = invn[ol];
  const ushort4 a = *(const ushort4*)(qkv + (size_t)s0 * NQKV + c);
  const ushort4 bq = *(const ushort4*)(qkv + (size_t)(s0 + 1) * NQKV + c);
  ushort4 rr;
  rr.x = f2bf((b2f(a.x) * m0 + b2f(bq.x) * m1) * inv);
  rr.y = f2bf((b2f(a.y) * m0 + b2f(bq.y) * m1) * inv);
  rr.z = f2bf((b2f(a.z) * m0 + b2f(bq.z) * m1) * inv);
  rr.w = f2bf((b2f(a.w) * m0 + b2f(bq.w) * m1) * inv);
  *(ushort4*)(qp + (size_t)ol * DD + c) = rr;
}

// ---------------------------------------------------------------- attention
__constant__ float c_slopes[12] = {
    0.5f, 0.25f, 0.125f, 0.0625f, 0.03125f, 0.015625f, 0.0078125f, 0.00390625f,
    0.70710678118654757f, 0.35355339059327379f, 0.17677669529663689f,
    0.088388347648318447f};

// one thread per pooled query row; flash-style online softmax over 8 key tiles
__global__ __launch_bounds__(128) void attn_fused(const unsigned short* __restrict__ qp,
                                                  const unsigned short* __restrict__ qkv,
                                                  const float* __restrict__ kbias,
                                                  const unsigned char* __restrict__ nmask,
                                                  float* __restrict__ out) {
  const int t = threadIdx.x;
  const int o = blockIdx.x * 128 + t;
  const int h = blockIdx.y;
  const int b = blockIdx.z;

  __shared__ float kt[64][64];
  __shared__ float vt[64][64];
  __shared__ float kb[64];

  float q[64];
  const unsigned short* qrow = qp + (size_t)(b * OL + o) * DD + h * HDIM;
#pragma unroll
  for (int i = 0; i < 16; ++i) {
    ushort4 u = ((const ushort4*)qrow)[i];
    q[4 * i + 0] = b2f(u.x); q[4 * i + 1] = b2f(u.y);
    q[4 * i + 2] = b2f(u.z); q[4 * i + 3] = b2f(u.w);
  }
  const float slope = c_slopes[h];
  const bool qm = nmask[b * OL + o] != 0;

  float mrun = -1e30f, l = 0.f;
  float acc[64];
#pragma unroll
  for (int d = 0; d < 64; ++d) acc[d] = 0.f;

  const int sr = t >> 1, sh = (t & 1) * 32;

  for (int tile = 0; tile < 8; ++tile) {
    const int key0 = tile * 64;
    __syncthreads();
    {
      const unsigned short* kp =
          qkv + (size_t)(b * SS + key0 + sr) * NQKV + DD + h * HDIM + sh;
      const unsigned short* vp = kp + DD;
#pragma unroll
      for (int i = 0; i < 8; ++i) {
        ushort4 u = ((const ushort4*)kp)[i];
        kt[sr][sh + 4 * i + 0] = b2f(u.x); kt[sr][sh + 4 * i + 1] = b2f(u.y);
        kt[sr][sh + 4 * i + 2] = b2f(u.z); kt[sr][sh + 4 * i + 3] = b2f(u.w);
      }
#pragma unroll
      for (int i = 0; i < 8; ++i) {
        ushort4 u = ((const ushort4*)vp)[i];
        vt[sr][sh + 4 * i + 0] = b2f(u.x); vt[sr][sh + 4 * i + 1] = b2f(u.y);
        vt[sr][sh + 4 * i + 2] = b2f(u.z); vt[sr][sh + 4 * i + 3] = b2f(u.w);
      }
      if (t < 64) kb[t] = kbias[b * SS + key0 + t];
    }
    __syncthreads();

#pragma unroll
    for (int sub = 0; sub < 4; ++sub) {
      float s[16];
#pragma unroll
      for (int j = 0; j < 16; ++j) s[j] = 0.f;
#pragma unroll
      for (int d0 = 0; d0 < 64; d0 += 4) {
#pragma unroll
        for (int j = 0; j < 16; ++j) {
          const float4 kv = *(const float4*)&kt[sub * 16 + j][d0];
          s[j] += q[d0] * kv.x + q[d0 + 1] * kv.y + q[d0 + 2] * kv.z + q[d0 + 3] * kv.w;
        }
      }
      float tmax = -1e30f;
#pragma unroll
      for (int j = 0; j < 16; ++j) {
        const int key = key0 + sub * 16 + j;
        const float biasv = qm ? kb[sub * 16 + j] : -10000.f;
        int rel = key - o; if (rel < 0) rel = -rel;
        s[j] = s[j] * 0.125f + biasv - slope * (float)rel;
        tmax = fmaxf(tmax, s[j]);
      }
      if (tmax > mrun) {
        const float sc = __expf(mrun - tmax);
        l *= sc;
#pragma unroll
        for (int d = 0; d < 64; ++d) acc[d] *= sc;
        mrun = tmax;
      }
#pragma unroll
      for (int j = 0; j < 16; ++j) { s[j] = __expf(s[j] - mrun); l += s[j]; }
#pragma unroll
      for (int d0 = 0; d0 < 64; d0 += 4) {
#pragma unroll
        for (int j = 0; j < 16; ++j) {
          const float4 vv = *(const float4*)&vt[sub * 16 + j][d0];
          acc[d0 + 0] += s[j] * vv.x; acc[d0 + 1] += s[j] * vv.y;
          acc[d0 + 2] += s[j] * vv.z; acc[d0 + 3] += s[j] * vv.w;
        }
      }
    }
  }
  const float rl = 1.f / l;
  float* op = out + (size_t)(b * OL + o) * DD + h * HDIM;
#pragma unroll
  for (int d0 = 0; d0 < 64; d0 += 4) {
    float4 ov;
    ov.x = acc[d0] * rl; ov.y = acc[d0 + 1] * rl;
    ov.z = acc[d0 + 2] * rl; ov.w = acc[d0 + 3] * rl;
    *(float4*)(op + d0) = ov;
  }
}

// ---------------------------------------------------------------- launch
extern "C" void kernel_launch(void* const* d_in, const int* in_sizes, int n_in,
                              void* d_out, int out_size, void* d_ws, size_t ws_size,
                              hipStream_t stream) {
  const float* hidden = (const float*)d_in[0];
  const void* maskraw = d_in[1];
  const float* W = (const float*)d_in[2];
  const float* bias = (const float*)d_in[3];
  float* out = (float*)d_out;

  char* ws = (char*)d_ws;
  // ws layout (bytes):
  unsigned short* Abf = (unsigned short*)(ws);                 // 25,165,824
  unsigned short* Btb = (unsigned short*)(ws + 25165824);      //  3,538,944
  unsigned short* qkv = (unsigned short*)(ws + 28704768);      // 75,497,472
  unsigned short* qp  = (unsigned short*)(ws + 104202240);     // 12,582,912
  float* kbias        = (float*)(ws + 116785152);              //     65,536
  float* invn         = (float*)(ws + 116850688);              //     32,768
  unsigned char* nmask = (unsigned char*)(ws + 116883456);     //      8,192

  float* out_nm = out + (size_t)BB * OL * DD;  // new_mask part of d_out

  conv_f32_bf16<<<(GM * DD / 4 + 255) / 256, 256, 0, stream>>>(hidden, Abf, GM * DD / 4);
  conv_f32_bf16<<<(NQKV * DD / 4 + 255) / 256, 256, 0, stream>>>(W, Btb, NQKV * DD / 4);
  prep_mask<<<BB, SS, 0, stream>>>(maskraw, kbias, invn, nmask, out_nm);
  gemm_qkv<<<dim3(NQKV / 128, GM / 128), 256, 0, stream>>>(Abf, Btb, bias, qkv);
  pool_q<<<(BB * OL * DD / 4 + 255) / 256, 256, 0, stream>>>(qkv, kbias, invn, qp);
  attn_fused<<<dim3(2, HH, BB), 128, 0, stream>>>(qp, qkv, kbias, nmask, out);
}

// Round 2
// 310.847 us; speedup vs baseline: 1.9716x; 1.9716x over previous
//
#include <hip/hip_runtime.h>

// Problem constants
#define BB 32
#define SS 512
#define DD 768
#define HH 12
#define HDIM 64
#define OL 256        // pooled query length
#define NQKV 2304     // 3*DD
#define GM (BB*SS)    // 16384 rows into the QKV GEMM

typedef __bf16 bf16_t;
typedef bf16_t bf16x8 __attribute__((ext_vector_type(8)));
typedef float f32x4 __attribute__((ext_vector_type(4)));

__device__ __forceinline__ unsigned short f2bf(float f) {
  unsigned u = __float_as_uint(f);
  u = u + 0x7FFFu + ((u >> 16) & 1u);   // RNE
  return (unsigned short)(u >> 16);
}
__device__ __forceinline__ float b2f(unsigned short s) {
  return __uint_as_float(((unsigned)s) << 16);
}

// ---------------------------------------------------------------- conversions
__global__ void conv_f32_bf16(const float* __restrict__ in,
                              unsigned short* __restrict__ out, int n4) {
  int i = blockIdx.x * blockDim.x + threadIdx.x;
  if (i >= n4) return;
  float4 v = ((const float4*)in)[i];
  ushort4 o;
  o.x = f2bf(v.x); o.y = f2bf(v.y); o.z = f2bf(v.z); o.w = f2bf(v.w);
  ((ushort4*)out)[i] = o;
}

// ---------------------------------------------------------------- mask prep
__global__ void prep_mask(const void* __restrict__ mraw,
                          float* __restrict__ kbias,
                          float* __restrict__ invn,
                          unsigned char* __restrict__ nmask,
                          float* __restrict__ out_nm) {
  int b = blockIdx.x, t = threadIdx.x;
  const unsigned char* mb = (const unsigned char*)mraw;
  bool isbyte = (mb[1] != 0);
  int idx = b * SS + t;
  int mv = isbyte ? (int)(mb[idx] != 0) : (int)(((const int*)mraw)[idx] != 0);
  kbias[idx] = mv ? 0.f : -10000.f;
  if (t < OL) {
    int i0 = b * SS + 2 * t, i1 = i0 + 1;
    int m0 = isbyte ? (int)(mb[i0] != 0) : (int)(((const int*)mraw)[i0] != 0);
    int m1 = isbyte ? (int)(mb[i1] != 0) : (int)(((const int*)mraw)[i1] != 0);
    int n = m0 + m1;
    invn[b * OL + t] = (n > 0) ? 1.f / (float)n : 1.f;
    nmask[b * OL + t] = (n > 0) ? 1 : 0;
    out_nm[b * OL + t] = (n > 0) ? 1.f : 0.f;   // second tuple output
  }
}

// ---------------------------------------------------------------- QKV GEMM
__global__ __launch_bounds__(256) void gemm_qkv(const unsigned short* __restrict__ A,
                                                const unsigned short* __restrict__ Bt,
                                                const float* __restrict__ bias,
                                                unsigned short* __restrict__ C) {
  __shared__ unsigned short sA[128 * 32];
  __shared__ unsigned short sB[128 * 32];
  const int t = threadIdx.x;
  const int lane = t & 63;
  const int w = t >> 6;
  const int wr = w >> 1, wc = w & 1;
  const int m0 = blockIdx.y * 128, n0 = blockIdx.x * 128;

  f32x4 acc[4][4] = {};

  const int r = t >> 2, cs = t & 3;
  const unsigned short* ga0 = A + (size_t)(m0 + r) * DD + cs * 8;
  const unsigned short* ga1 = ga0 + (size_t)64 * DD;
  const unsigned short* gb0 = Bt + (size_t)(n0 + r) * DD + cs * 8;
  const unsigned short* gb1 = gb0 + (size_t)64 * DD;
  const int wvb = __builtin_amdgcn_readfirstlane(w << 10);
  char* sAb = (char*)sA;
  char* sBb = (char*)sB;

  const int fr = lane & 15;
  const int kk = (lane >> 4) * 8;

  for (int kt = 0; kt < DD; kt += 32) {
    __builtin_amdgcn_global_load_lds(
        (const __attribute__((address_space(1))) unsigned int*)(ga0 + kt),
        (__attribute__((address_space(3))) unsigned int*)(sAb + wvb), 16, 0, 0);
    __builtin_amdgcn_global_load_lds(
        (const __attribute__((address_space(1))) unsigned int*)(ga1 + kt),
        (__attribute__((address_space(3))) unsigned int*)(sAb + 4096 + wvb), 16, 0, 0);
    __builtin_amdgcn_global_load_lds(
        (const __attribute__((address_space(1))) unsigned int*)(gb0 + kt),
        (__attribute__((address_space(3))) unsigned int*)(sBb + wvb), 16, 0, 0);
    __builtin_amdgcn_global_load_lds(
        (const __attribute__((address_space(1))) unsigned int*)(gb1 + kt),
        (__attribute__((address_space(3))) unsigned int*)(sBb + 4096 + wvb), 16, 0, 0);
    __syncthreads();

    bf16x8 av[4], bv[4];
#pragma unroll
    for (int m = 0; m < 4; ++m)
      av[m] = *(const bf16x8*)(sA + (wr * 64 + m * 16 + fr) * 32 + kk);
#pragma unroll
    for (int n = 0; n < 4; ++n)
      bv[n] = *(const bf16x8*)(sB + (wc * 64 + n * 16 + fr) * 32 + kk);
#pragma unroll
    for (int m = 0; m < 4; ++m)
#pragma unroll
      for (int n = 0; n < 4; ++n)
        acc[m][n] = __builtin_amdgcn_mfma_f32_16x16x32_bf16(av[m], bv[n], acc[m][n], 0, 0, 0);
    __syncthreads();
  }

#pragma unroll
  for (int m = 0; m < 4; ++m) {
#pragma unroll
    for (int n = 0; n < 4; ++n) {
      const int gm = m0 + wr * 64 + m * 16 + (lane >> 4) * 4;
      const int gn = n0 + wc * 64 + n * 16 + fr;
      const float bvs = bias[gn];
#pragma unroll
      for (int j = 0; j < 4; ++j)
        C[(size_t)(gm + j) * NQKV + gn] = f2bf(acc[m][n][j] + bvs);
    }
  }
}

// ---------------------------------------------------------------- Q pooling
__global__ void pool_q(const unsigned short* __restrict__ qkv,
                       const float* __restrict__ kbias,
                       const float* __restrict__ invn,
                       unsigned short* __restrict__ qp) {
  int i = blockIdx.x * blockDim.x + threadIdx.x;
  if (i >= (BB * OL * DD) / 4) return;
  int c = (i * 4) % DD;
  int ol = (i * 4) / DD;    // b*OL + o
  int b = ol >> 8, o = ol & 255;
  int s0 = b * SS + 2 * o;
  float m0 = (kbias[s0] == 0.f) ? 1.f : 0.f;
  float m1 = (kbias[s0 + 1] == 0.f) ? 1.f : 0.f;
  float inv = invn[ol];
  const ushort4 a = *(const ushort4*)(qkv + (size_t)s0 * NQKV + c);
  const ushort4 bq = *(const ushort4*)(qkv + (size_t)(s0 + 1) * NQKV + c);
  ushort4 rr;
  rr.x = f2bf((b2f(a.x) * m0 + b2f(bq.x) * m1) * inv);
  rr.y = f2bf((b2f(a.y) * m0 + b2f(bq.y) * m1) * inv);
  rr.z = f2bf((b2f(a.z) * m0 + b2f(bq.z) * m1) * inv);
  rr.w = f2bf((b2f(a.w) * m0 + b2f(bq.w) * m1) * inv);
  *(ushort4*)(qp + (size_t)ol * DD + c) = rr;
}

// ---------------------------------------------------------------- V transpose
// vT[b][h][d][s] <- qkv[b*512+s][1536 + h*64 + d]
__global__ __launch_bounds__(256) void transp_v(const unsigned short* __restrict__ qkv,
                                                unsigned short* __restrict__ vT) {
  const int s0 = blockIdx.x * 64;
  const int h = blockIdx.y, b = blockIdx.z;
  __shared__ unsigned short tile[64][68];   // 68 pad: 136B rows keep 8B align
  const int t = threadIdx.x;
  const int sl = t >> 4, dl = (t & 15) * 4;
#pragma unroll
  for (int i = 0; i < 4; ++i) {
    ushort4 u = *(const ushort4*)(qkv + (size_t)(b * SS + s0 + sl + i * 16) * NQKV +
                                  2 * DD + h * HDIM + dl);
    *(ushort4*)&tile[sl + i * 16][dl] = u;
  }
  __syncthreads();
  const int d2 = t >> 4, s2 = (t & 15) * 4;
#pragma unroll
  for (int i = 0; i < 4; ++i) {
    const int d = d2 + i * 16;
    ushort4 u;
    u.x = tile[s2 + 0][d]; u.y = tile[s2 + 1][d];
    u.z = tile[s2 + 2][d]; u.w = tile[s2 + 3][d];
    *(ushort4*)(vT + ((size_t)((b * HH + h) * HDIM + d)) * SS + s0 + s2) = u;
  }
}

// ---------------------------------------------------------------- attention
__constant__ float c_slopes[12] = {
    0.5f, 0.25f, 0.125f, 0.0625f, 0.03125f, 0.015625f, 0.0078125f, 0.00390625f,
    0.70710678118654757f, 0.35355339059327379f, 0.17677669529663689f,
    0.088388347648318447f};

// One wave per (b, h, 64-query tile). MFMA QK^T + online softmax + MFMA PV.
// K LDS tile: logical [key][d], byte = key*128 + d*2, XOR-swz ((key&7)<<4)
// V LDS tile: logical [d][key], byte = d*128 + key*2, XOR-swz ((d&7)<<4)
// P LDS tile: logical [q][key],  byte = q*128 + key*2, XOR-swz ((q&7)<<4)
__global__ __launch_bounds__(64, 2) void attn_mfma(
    const unsigned short* __restrict__ qp,    // [B][OL][768] bf16
    const unsigned short* __restrict__ qkv,   // [B*S][2304] bf16
    const unsigned short* __restrict__ vT,    // [B][H][64][512] bf16
    const float* __restrict__ kbias,          // [B][S]
    const unsigned char* __restrict__ nmask,  // [B][OL]
    float* __restrict__ out) {                // [B][OL][768]
  const int lane = threadIdx.x;
  const int fr = lane & 15, hi = lane >> 4;
  const int q0 = blockIdx.x * 64;
  const int h = blockIdx.y, b = blockIdx.z;

  __shared__ unsigned short kt[4096];
  __shared__ unsigned short vt[4096];
  __shared__ unsigned short pt[4096];
  __shared__ float kb[64];
  char* ktb = (char*)kt; char* vtb = (char*)vt; char* ptb = (char*)pt;

  // Q fragments: A-operand, row = q0+m*16+fr, k(d) = ks*32 + hi*8 (+0..7)
  bf16x8 qf[4][2];
#pragma unroll
  for (int m = 0; m < 4; ++m)
#pragma unroll
    for (int ks = 0; ks < 2; ++ks)
      qf[m][ks] = *(const bf16x8*)(qp + (size_t)(b * OL + q0 + m * 16 + fr) * DD +
                                   h * HDIM + ks * 32 + hi * 8);

  int qmbits = 0;
#pragma unroll
  for (int m = 0; m < 4; ++m)
#pragma unroll
    for (int j = 0; j < 4; ++j)
      if (nmask[b * OL + q0 + m * 16 + hi * 4 + j]) qmbits |= 1 << (m * 4 + j);

  const float slope = c_slopes[h];
  f32x4 oacc[4][4] = {};
  float mrun[4][4], lpart[4][4];
#pragma unroll
  for (int m = 0; m < 4; ++m)
#pragma unroll
    for (int j = 0; j < 4; ++j) { mrun[m][j] = -1e30f; lpart[m][j] = 0.f; }

  // pre-swizzled linear staging: issue i covers rows i*8+srow, lane writes 16B
  const int srow = lane >> 3;                        // 0..7
  const int scol = ((lane & 7) ^ (lane >> 3)) * 8;   // element offset in row

  for (int tile = 0; tile < 8; ++tile) {
    const int key0 = tile * 64;
    __syncthreads();
#pragma unroll
    for (int i = 0; i < 8; ++i)
      __builtin_amdgcn_global_load_lds(
          (const __attribute__((address_space(1))) unsigned int*)
              (qkv + (size_t)(b * SS + key0 + i * 8 + srow) * NQKV + DD + h * HDIM + scol),
          (__attribute__((address_space(3))) unsigned int*)(ktb + i * 1024), 16, 0, 0);
#pragma unroll
    for (int i = 0; i < 8; ++i)
      __builtin_amdgcn_global_load_lds(
          (const __attribute__((address_space(1))) unsigned int*)
              (vT + (size_t)((b * HH + h) * HDIM + i * 8 + srow) * SS + key0 + scol),
          (__attribute__((address_space(3))) unsigned int*)(vtb + i * 1024), 16, 0, 0);
    kb[lane] = kbias[b * SS + key0 + lane];
    __syncthreads();

    // ---- QK^T
    f32x4 sacc[4][4] = {};
#pragma unroll
    for (int ks = 0; ks < 2; ++ks) {
      bf16x8 kf[4];
#pragma unroll
      for (int n = 0; n < 4; ++n) {
        const int by = ((n * 16 + fr) * 128 + (ks * 64 + hi * 16)) ^ ((fr & 7) << 4);
        kf[n] = *(const bf16x8*)(ktb + by);
      }
#pragma unroll
      for (int m = 0; m < 4; ++m)
#pragma unroll
        for (int n = 0; n < 4; ++n)
          sacc[m][n] = __builtin_amdgcn_mfma_f32_16x16x32_bf16(qf[m][ks], kf[n], sacc[m][n], 0, 0, 0);
    }

    // ---- bias + alibi + online softmax; P -> LDS (bf16)
#pragma unroll
    for (int m = 0; m < 4; ++m) {
#pragma unroll
      for (int j = 0; j < 4; ++j) {
        const int q = q0 + m * 16 + hi * 4 + j;
        const bool qm = (qmbits >> (m * 4 + j)) & 1;
        float mx = -1e30f;
#pragma unroll
        for (int n = 0; n < 4; ++n) {
          const int key = key0 + n * 16 + fr;
          const float biasv = qm ? kb[n * 16 + fr] : -10000.f;
          int rel = key - q; rel = rel < 0 ? -rel : rel;
          float v = sacc[m][n][j] * 0.125f + biasv - slope * (float)rel;
          sacc[m][n][j] = v;
          mx = fmaxf(mx, v);
        }
        mx = fmaxf(mx, __shfl_xor(mx, 1, 64));
        mx = fmaxf(mx, __shfl_xor(mx, 2, 64));
        mx = fmaxf(mx, __shfl_xor(mx, 4, 64));
        mx = fmaxf(mx, __shfl_xor(mx, 8, 64));
        const float mn = fmaxf(mrun[m][j], mx);
        const float sc = __expf(mrun[m][j] - mn);
        mrun[m][j] = mn;
        float lp = lpart[m][j] * sc;
#pragma unroll
        for (int nd = 0; nd < 4; ++nd) oacc[m][nd][j] *= sc;
#pragma unroll
        for (int n = 0; n < 4; ++n) {
          const float p = __expf(sacc[m][n][j] - mn);
          lp += p;
          const int by = ((m * 16 + hi * 4 + j) * 128 + (n * 16 + fr) * 2) ^
                         (((hi * 4 + j) & 7) << 4);
          *(unsigned short*)(ptb + by) = f2bf(p);
        }
        lpart[m][j] = lp;
      }
    }
    __syncthreads();

    // ---- PV
#pragma unroll
    for (int ks = 0; ks < 2; ++ks) {
      bf16x8 pf[4], vf[4];
#pragma unroll
      for (int m = 0; m < 4; ++m) {
        const int by = ((m * 16 + fr) * 128 + (ks * 64 + hi * 16)) ^ ((fr & 7) << 4);
        pf[m] = *(const bf16x8*)(ptb + by);
      }
#pragma unroll
      for (int nd = 0; nd < 4; ++nd) {
        const int by = ((nd * 16 + fr) * 128 + (ks * 64 + hi * 16)) ^ ((fr & 7) << 4);
        vf[nd] = *(const bf16x8*)(vtb + by);
      }
#pragma unroll
      for (int m = 0; m < 4; ++m)
#pragma unroll
        for (int nd = 0; nd < 4; ++nd)
          oacc[m][nd] = __builtin_amdgcn_mfma_f32_16x16x32_bf16(pf[m], vf[nd], oacc[m][nd], 0, 0, 0);
    }
  }

  // ---- epilogue: reduce l across the 16-lane group, normalize, store
#pragma unroll
  for (int m = 0; m < 4; ++m)
#pragma unroll
    for (int j = 0; j < 4; ++j) {
      float l = lpart[m][j];
      l += __shfl_xor(l, 1, 64);
      l += __shfl_xor(l, 2, 64);
      l += __shfl_xor(l, 4, 64);
      l += __shfl_xor(l, 8, 64);
      const float rl = 1.f / l;
      float* op = out + (size_t)(b * OL + q0 + m * 16 + hi * 4 + j) * DD + h * HDIM;
#pragma unroll
      for (int nd = 0; nd < 4; ++nd)
        op[nd * 16 + fr] = oacc[m][nd][j] * rl;
    }
}

// ---------------------------------------------------------------- launch
extern "C" void kernel_launch(void* const* d_in, const int* in_sizes, int n_in,
                              void* d_out, int out_size, void* d_ws, size_t ws_size,
                              hipStream_t stream) {
  const float* hidden = (const float*)d_in[0];
  const void* maskraw = d_in[1];
  const float* W = (const float*)d_in[2];
  const float* bias = (const float*)d_in[3];
  float* out = (float*)d_out;

  char* ws = (char*)d_ws;
  unsigned short* Abf = (unsigned short*)(ws);                 // 25,165,824 B
  unsigned short* vT  = (unsigned short*)(ws);                 // reuses Abf after GEMM
  unsigned short* Btb = (unsigned short*)(ws + 25165824);      //  3,538,944 B
  unsigned short* qkv = (unsigned short*)(ws + 28704768);      // 75,497,472 B
  unsigned short* qp  = (unsigned short*)(ws + 104202240);     // 12,582,912 B
  float* kbias        = (float*)(ws + 116785152);              //     65,536 B
  float* invn         = (float*)(ws + 116850688);              //     32,768 B
  unsigned char* nmask = (unsigned char*)(ws + 116883456);     //      8,192 B

  float* out_nm = out + (size_t)BB * OL * DD;  // new_mask part of d_out

  conv_f32_bf16<<<(GM * DD / 4 + 255) / 256, 256, 0, stream>>>(hidden, Abf, GM * DD / 4);
  conv_f32_bf16<<<(NQKV * DD / 4 + 255) / 256, 256, 0, stream>>>(W, Btb, NQKV * DD / 4);
  prep_mask<<<BB, SS, 0, stream>>>(maskraw, kbias, invn, nmask, out_nm);
  gemm_qkv<<<dim3(NQKV / 128, GM / 128), 256, 0, stream>>>(Abf, Btb, bias, qkv);
  pool_q<<<(BB * OL * DD / 4 + 255) / 256, 256, 0, stream>>>(qkv, kbias, invn, qp);
  transp_v<<<dim3(SS / 64, HH, BB), 256, 0, stream>>>(qkv, vT);
  attn_mfma<<<dim3(OL / 64, HH, BB), 64, 0, stream>>>(qp, qkv, vT, kbias, nmask, out);
}

// Round 3
// 166.088 us; speedup vs baseline: 3.6901x; 1.8716x over previous
//
#include <hip/hip_runtime.h>

// Problem constants
#define BB 32
#define SS 512
#define DD 768
#define HH 12
#define HDIM 64
#define OL 256        // pooled query length
#define NQKV 2304     // 3*DD
#define GM (BB*SS)    // 16384 rows into the QKV GEMM

#define LOG2E 1.44269504088896f
#define NEG2 (-14426.9504089f)   // -10000 * log2(e)

typedef __bf16 bf16_t;
typedef bf16_t bf16x8 __attribute__((ext_vector_type(8)));
typedef float f32x4 __attribute__((ext_vector_type(4)));

__device__ __forceinline__ unsigned short f2bf(float f) {
  unsigned u = __float_as_uint(f);
  u = u + 0x7FFFu + ((u >> 16) & 1u);   // RNE
  return (unsigned short)(u >> 16);
}
__device__ __forceinline__ float b2f(unsigned short s) {
  return __uint_as_float(((unsigned)s) << 16);
}

// ---------------------------------------------------------------- conversions
__global__ void conv_f32_bf16(const float* __restrict__ in,
                              unsigned short* __restrict__ out, int n4) {
  int i = blockIdx.x * blockDim.x + threadIdx.x;
  if (i >= n4) return;
  float4 v = ((const float4*)in)[i];
  ushort4 o;
  o.x = f2bf(v.x); o.y = f2bf(v.y); o.z = f2bf(v.z); o.w = f2bf(v.w);
  ((ushort4*)out)[i] = o;
}

// ---------------------------------------------------------------- mask prep
// kbias is stored PRE-SCALED by log2(e): 0 for valid, -14427 for masked.
__global__ void prep_mask(const void* __restrict__ mraw,
                          float* __restrict__ kbias,
                          float* __restrict__ invn,
                          unsigned char* __restrict__ nmask,
                          float* __restrict__ out_nm) {
  int b = blockIdx.x, t = threadIdx.x;
  const unsigned char* mb = (const unsigned char*)mraw;
  bool isbyte = (mb[1] != 0);
  int idx = b * SS + t;
  int mv = isbyte ? (int)(mb[idx] != 0) : (int)(((const int*)mraw)[idx] != 0);
  kbias[idx] = mv ? 0.f : NEG2;
  if (t < OL) {
    int i0 = b * SS + 2 * t, i1 = i0 + 1;
    int m0 = isbyte ? (int)(mb[i0] != 0) : (int)(((const int*)mraw)[i0] != 0);
    int m1 = isbyte ? (int)(mb[i1] != 0) : (int)(((const int*)mraw)[i1] != 0);
    int n = m0 + m1;
    invn[b * OL + t] = (n > 0) ? 1.f / (float)n : 1.f;
    nmask[b * OL + t] = (n > 0) ? 1 : 0;
    out_nm[b * OL + t] = (n > 0) ? 1.f : 0.f;   // second tuple output
  }
}

// ---------------------------------------------------------------- QKV GEMM
__global__ __launch_bounds__(256) void gemm_qkv(const unsigned short* __restrict__ A,
                                                const unsigned short* __restrict__ Bt,
                                                const float* __restrict__ bias,
                                                unsigned short* __restrict__ C) {
  __shared__ unsigned short sA[128 * 32];
  __shared__ unsigned short sB[128 * 32];
  const int t = threadIdx.x;
  const int lane = t & 63;
  const int w = t >> 6;
  const int wr = w >> 1, wc = w & 1;
  const int m0 = blockIdx.y * 128, n0 = blockIdx.x * 128;

  f32x4 acc[4][4] = {};

  const int r = t >> 2, cs = t & 3;
  const unsigned short* ga0 = A + (size_t)(m0 + r) * DD + cs * 8;
  const unsigned short* ga1 = ga0 + (size_t)64 * DD;
  const unsigned short* gb0 = Bt + (size_t)(n0 + r) * DD + cs * 8;
  const unsigned short* gb1 = gb0 + (size_t)64 * DD;
  const int wvb = __builtin_amdgcn_readfirstlane(w << 10);
  char* sAb = (char*)sA;
  char* sBb = (char*)sB;

  const int fr = lane & 15;
  const int kk = (lane >> 4) * 8;

  for (int kt = 0; kt < DD; kt += 32) {
    __builtin_amdgcn_global_load_lds(
        (const __attribute__((address_space(1))) unsigned int*)(ga0 + kt),
        (__attribute__((address_space(3))) unsigned int*)(sAb + wvb), 16, 0, 0);
    __builtin_amdgcn_global_load_lds(
        (const __attribute__((address_space(1))) unsigned int*)(ga1 + kt),
        (__attribute__((address_space(3))) unsigned int*)(sAb + 4096 + wvb), 16, 0, 0);
    __builtin_amdgcn_global_load_lds(
        (const __attribute__((address_space(1))) unsigned int*)(gb0 + kt),
        (__attribute__((address_space(3))) unsigned int*)(sBb + wvb), 16, 0, 0);
    __builtin_amdgcn_global_load_lds(
        (const __attribute__((address_space(1))) unsigned int*)(gb1 + kt),
        (__attribute__((address_space(3))) unsigned int*)(sBb + 4096 + wvb), 16, 0, 0);
    __syncthreads();

    bf16x8 av[4], bv[4];
#pragma unroll
    for (int m = 0; m < 4; ++m)
      av[m] = *(const bf16x8*)(sA + (wr * 64 + m * 16 + fr) * 32 + kk);
#pragma unroll
    for (int n = 0; n < 4; ++n)
      bv[n] = *(const bf16x8*)(sB + (wc * 64 + n * 16 + fr) * 32 + kk);
#pragma unroll
    for (int m = 0; m < 4; ++m)
#pragma unroll
      for (int n = 0; n < 4; ++n)
        acc[m][n] = __builtin_amdgcn_mfma_f32_16x16x32_bf16(av[m], bv[n], acc[m][n], 0, 0, 0);
    __syncthreads();
  }

#pragma unroll
  for (int m = 0; m < 4; ++m) {
#pragma unroll
    for (int n = 0; n < 4; ++n) {
      const int gm = m0 + wr * 64 + m * 16 + (lane >> 4) * 4;
      const int gn = n0 + wc * 64 + n * 16 + fr;
      const float bvs = bias[gn];
#pragma unroll
      for (int j = 0; j < 4; ++j)
        C[(size_t)(gm + j) * NQKV + gn] = f2bf(acc[m][n][j] + bvs);
    }
  }
}

// ---------------------------------------------------------------- Q pooling
__global__ void pool_q(const unsigned short* __restrict__ qkv,
                       const float* __restrict__ kbias,
                       const float* __restrict__ invn,
                       unsigned short* __restrict__ qp) {
  int i = blockIdx.x * blockDim.x + threadIdx.x;
  if (i >= (BB * OL * DD) / 4) return;
  int c = (i * 4) % DD;
  int ol = (i * 4) / DD;    // b*OL + o
  int b = ol >> 8, o = ol & 255;
  int s0 = b * SS + 2 * o;
  float m0 = (kbias[s0] == 0.f) ? 1.f : 0.f;
  float m1 = (kbias[s0 + 1] == 0.f) ? 1.f : 0.f;
  float inv = invn[ol];
  const ushort4 a = *(const ushort4*)(qkv + (size_t)s0 * NQKV + c);
  const ushort4 bq = *(const ushort4*)(qkv + (size_t)(s0 + 1) * NQKV + c);
  ushort4 rr;
  rr.x = f2bf((b2f(a.x) * m0 + b2f(bq.x) * m1) * inv);
  rr.y = f2bf((b2f(a.y) * m0 + b2f(bq.y) * m1) * inv);
  rr.z = f2bf((b2f(a.z) * m0 + b2f(bq.z) * m1) * inv);
  rr.w = f2bf((b2f(a.w) * m0 + b2f(bq.w) * m1) * inv);
  *(ushort4*)(qp + (size_t)ol * DD + c) = rr;
}

// ---------------------------------------------------------------- V transpose
__global__ __launch_bounds__(256) void transp_v(const unsigned short* __restrict__ qkv,
                                                unsigned short* __restrict__ vT) {
  const int s0 = blockIdx.x * 64;
  const int h = blockIdx.y, b = blockIdx.z;
  __shared__ unsigned short tile[64][68];
  const int t = threadIdx.x;
  const int sl = t >> 4, dl = (t & 15) * 4;
#pragma unroll
  for (int i = 0; i < 4; ++i) {
    ushort4 u = *(const ushort4*)(qkv + (size_t)(b * SS + s0 + sl + i * 16) * NQKV +
                                  2 * DD + h * HDIM + dl);
    *(ushort4*)&tile[sl + i * 16][dl] = u;
  }
  __syncthreads();
  const int d2 = t >> 4, s2 = (t & 15) * 4;
#pragma unroll
  for (int i = 0; i < 4; ++i) {
    const int d = d2 + i * 16;
    ushort4 u;
    u.x = tile[s2 + 0][d]; u.y = tile[s2 + 1][d];
    u.z = tile[s2 + 2][d]; u.w = tile[s2 + 3][d];
    *(ushort4*)(vT + ((size_t)((b * HH + h) * HDIM + d)) * SS + s0 + s2) = u;
  }
}

// ---------------------------------------------------------------- attention
// slopes pre-scaled by log2(e)
__constant__ float c_slopes2[12] = {
    0.72134752f, 0.36067376f, 0.18033688f, 0.09016844f,
    0.04508422f, 0.02254211f, 0.011271055f, 0.0056355275f,
    1.02013945f, 0.51006972f, 0.25503486f, 0.12751743f};

// One wave per (b, h, 64-query tile). XCD-chunked swizzle, double-buffered
// K/V staging with counted vmcnt, fixed-max log2-domain softmax.
// LDS map (bytes): ktA 0, ktB 8192, vtA 16384, vtB 24576, pt 32768,
//                  kb 40960 (512 f32). Epilogue O-tile reuses [0, 17408).
__global__ __launch_bounds__(64) void attn_mfma(
    const unsigned short* __restrict__ qp,    // [B][OL][768] bf16
    const unsigned short* __restrict__ qkv,   // [B*S][2304] bf16
    const unsigned short* __restrict__ vT,    // [B][H][64][512] bf16
    const float* __restrict__ kbias,          // [B][S], pre-scaled log2e
    const unsigned char* __restrict__ nmask,  // [B][OL]
    float* __restrict__ out) {                // [B][OL][768]
  __shared__ __align__(16) char smem[43008];
  const int lane = threadIdx.x;
  const int fr = lane & 15, hi = lane >> 4;

  // XCD-chunked swizzle: 1536 blocks, 192 per XCD; tile is fastest logical dim
  const int p = blockIdx.x;
  const int l = (p & 7) * 192 + (p >> 3);
  const int q0 = (l & 3) * 64;
  const int bh = l >> 2;
  const int h = bh % HH, b = bh / HH;

  char* ptb = smem + 32768;
  float* kbl = (float*)(smem + 40960);

  // preload kbias row (512 floats) into LDS
  {
    const float4* src = (const float4*)(kbias + b * SS);
    float4 v0 = src[lane];
    float4 v1 = src[lane + 64];
    ((float4*)kbl)[lane] = v0;
    ((float4*)kbl)[lane + 64] = v1;
  }

  // Q fragments: A-operand, row = q0+m*16+fr, k(d) = ks*32 + hi*8 (+0..7)
  bf16x8 qf[4][2];
#pragma unroll
  for (int m = 0; m < 4; ++m)
#pragma unroll
    for (int ks = 0; ks < 2; ++ks)
      qf[m][ks] = *(const bf16x8*)(qp + (size_t)(b * OL + q0 + m * 16 + fr) * DD +
                                   h * HDIM + ks * 32 + hi * 8);

  int qmbits = 0;
#pragma unroll
  for (int m = 0; m < 4; ++m)
#pragma unroll
    for (int j = 0; j < 4; ++j)
      if (nmask[b * OL + q0 + m * 16 + hi * 4 + j]) qmbits |= 1 << (m * 4 + j);

  const float slope2 = c_slopes2[h];
  f32x4 oacc[4][4] = {};
  float lpart[4][4] = {};

  const int srow = lane >> 3;
  const int scol = ((lane & 7) ^ srow) * 8;

#define STAGE(TILE, BUF) do {                                                  \
    char* kd_ = smem + (BUF) * 8192;                                           \
    char* vd_ = smem + 16384 + (BUF) * 8192;                                   \
    const unsigned short* ks_ = qkv + (size_t)(b * SS + (TILE) * 64 + srow) * NQKV + DD + h * HDIM + scol; \
    const unsigned short* vs_ = vT + (size_t)((b * HH + h) * HDIM + srow) * SS + (TILE) * 64 + scol;       \
    _Pragma("unroll")                                                          \
    for (int i_ = 0; i_ < 8; ++i_) {                                           \
      __builtin_amdgcn_global_load_lds(                                        \
          (const __attribute__((address_space(1))) unsigned int*)(ks_ + (size_t)i_ * 8 * NQKV), \
          (__attribute__((address_space(3))) unsigned int*)(kd_ + i_ * 1024), 16, 0, 0);        \
      __builtin_amdgcn_global_load_lds(                                        \
          (const __attribute__((address_space(1))) unsigned int*)(vs_ + (size_t)i_ * 8 * SS),   \
          (__attribute__((address_space(3))) unsigned int*)(vd_ + i_ * 1024), 16, 0, 0);        \
    }                                                                          \
  } while (0)

  STAGE(0, 0);

  for (int tile = 0; tile < 8; ++tile) {
    const int cur = tile & 1;
    const int key0 = tile * 64;
    if (tile < 7) {
      asm volatile("s_waitcnt lgkmcnt(0)" ::: "memory");
      STAGE(tile + 1, cur ^ 1);
      asm volatile("s_waitcnt vmcnt(16)" ::: "memory");
    } else {
      asm volatile("s_waitcnt vmcnt(0)" ::: "memory");
    }
    __builtin_amdgcn_sched_barrier(0);
    char* ktb = smem + cur * 8192;
    char* vtb = smem + 16384 + cur * 8192;

    // ---- QK^T
    f32x4 sacc[4][4] = {};
#pragma unroll
    for (int ks = 0; ks < 2; ++ks) {
      bf16x8 kf[4];
#pragma unroll
      for (int n = 0; n < 4; ++n) {
        const int by = ((n * 16 + fr) * 128 + (ks * 64 + hi * 16)) ^ ((fr & 7) << 4);
        kf[n] = *(const bf16x8*)(ktb + by);
      }
#pragma unroll
      for (int m = 0; m < 4; ++m)
#pragma unroll
        for (int n = 0; n < 4; ++n)
          sacc[m][n] = __builtin_amdgcn_mfma_f32_16x16x32_bf16(qf[m][ks], kf[n], sacc[m][n], 0, 0, 0);
    }

    // ---- fixed-max log2-domain softmax; P -> LDS (bf16)
    float kbv[4], keyfv[4];
#pragma unroll
    for (int n = 0; n < 4; ++n) {
      kbv[n] = kbl[key0 + n * 16 + fr];
      keyfv[n] = (float)(key0 + n * 16 + fr);
    }
#pragma unroll
    for (int m = 0; m < 4; ++m) {
#pragma unroll
      for (int j = 0; j < 4; ++j) {
        const bool qm = (qmbits >> (m * 4 + j)) & 1;
        const float qvf = (float)(q0 + m * 16 + hi * 4 + j);
        float lp = lpart[m][j];
#pragma unroll
        for (int n = 0; n < 4; ++n) {
          const float biasv = qm ? kbv[n] : 0.f;
          const float rel = fabsf(keyfv[n] - qvf);
          float tv = fmaf(sacc[m][n][j], 0.18033688011f, biasv);
          tv = fmaf(rel, -slope2, tv);
          float pe;
          asm("v_exp_f32 %0, %1" : "=v"(pe) : "v"(tv));
          lp += pe;
          const int by = ((m * 16 + hi * 4 + j) * 128 + (n * 16 + fr) * 2) ^
                         (((hi * 4 + j) & 7) << 4);
          *(unsigned short*)(ptb + by) = f2bf(pe);
        }
        lpart[m][j] = lp;
      }
    }
    asm volatile("s_waitcnt lgkmcnt(0)" ::: "memory");
    __builtin_amdgcn_sched_barrier(0);

    // ---- PV
#pragma unroll
    for (int ks = 0; ks < 2; ++ks) {
      bf16x8 pf[4], vf[4];
#pragma unroll
      for (int m = 0; m < 4; ++m) {
        const int by = ((m * 16 + fr) * 128 + (ks * 64 + hi * 16)) ^ ((fr & 7) << 4);
        pf[m] = *(const bf16x8*)(ptb + by);
      }
#pragma unroll
      for (int nd = 0; nd < 4; ++nd) {
        const int by = ((nd * 16 + fr) * 128 + (ks * 64 + hi * 16)) ^ ((fr & 7) << 4);
        vf[nd] = *(const bf16x8*)(vtb + by);
      }
#pragma unroll
      for (int m = 0; m < 4; ++m)
#pragma unroll
        for (int nd = 0; nd < 4; ++nd)
          oacc[m][nd] = __builtin_amdgcn_mfma_f32_16x16x32_bf16(pf[m], vf[nd], oacc[m][nd], 0, 0, 0);
    }
  }
#undef STAGE

  // ---- epilogue: reduce l, normalize, transpose via LDS, coalesced store
  float* ot = (float*)smem;   // 64 x 68 f32 tile (17408 B)
#pragma unroll
  for (int m = 0; m < 4; ++m)
#pragma unroll
    for (int j = 0; j < 4; ++j) {
      float lv = lpart[m][j];
      lv += __shfl_xor(lv, 1, 64);
      lv += __shfl_xor(lv, 2, 64);
      lv += __shfl_xor(lv, 4, 64);
      lv += __shfl_xor(lv, 8, 64);
      const float rl = 1.f / lv;
      const int row = m * 16 + hi * 4 + j;
#pragma unroll
      for (int nd = 0; nd < 4; ++nd)
        ot[row * 68 + nd * 16 + fr] = oacc[m][nd][j] * rl;
    }
  asm volatile("s_waitcnt lgkmcnt(0)" ::: "memory");
  __builtin_amdgcn_sched_barrier(0);
#pragma unroll
  for (int i = 0; i < 16; ++i) {
    const int idx = i * 64 + lane;       // float4 index
    const int row = idx >> 4, c4 = idx & 15;
    const float4 v = *(const float4*)&ot[row * 68 + c4 * 4];
    *(float4*)(out + (size_t)(b * OL + q0 + row) * DD + h * HDIM + c4 * 4) = v;
  }
}

// ---------------------------------------------------------------- launch
extern "C" void kernel_launch(void* const* d_in, const int* in_sizes, int n_in,
                              void* d_out, int out_size, void* d_ws, size_t ws_size,
                              hipStream_t stream) {
  const float* hidden = (const float*)d_in[0];
  const void* maskraw = d_in[1];
  const float* W = (const float*)d_in[2];
  const float* bias = (const float*)d_in[3];
  float* out = (float*)d_out;

  char* ws = (char*)d_ws;
  unsigned short* Abf = (unsigned short*)(ws);                 // 25,165,824 B
  unsigned short* vT  = (unsigned short*)(ws);                 // reuses Abf after GEMM
  unsigned short* Btb = (unsigned short*)(ws + 25165824);      //  3,538,944 B
  unsigned short* qkv = (unsigned short*)(ws + 28704768);      // 75,497,472 B
  unsigned short* qp  = (unsigned short*)(ws + 104202240);     // 12,582,912 B
  float* kbias        = (float*)(ws + 116785152);              //     65,536 B
  float* invn         = (float*)(ws + 116850688);              //     32,768 B
  unsigned char* nmask = (unsigned char*)(ws + 116883456);     //      8,192 B

  float* out_nm = out + (size_t)BB * OL * DD;  // new_mask part of d_out

  conv_f32_bf16<<<(GM * DD / 4 + 255) / 256, 256, 0, stream>>>(hidden, Abf, GM * DD / 4);
  conv_f32_bf16<<<(NQKV * DD / 4 + 255) / 256, 256, 0, stream>>>(W, Btb, NQKV * DD / 4);
  prep_mask<<<BB, SS, 0, stream>>>(maskraw, kbias, invn, nmask, out_nm);
  gemm_qkv<<<dim3(NQKV / 128, GM / 128), 256, 0, stream>>>(Abf, Btb, bias, qkv);
  pool_q<<<(BB * OL * DD / 4 + 255) / 256, 256, 0, stream>>>(qkv, kbias, invn, qp);
  transp_v<<<dim3(SS / 64, HH, BB), 256, 0, stream>>>(qkv, vT);
  attn_mfma<<<1536, 64, 0, stream>>>(qp, qkv, vT, kbias, nmask, out);
}

// Round 4
// 162.211 us; speedup vs baseline: 3.7783x; 1.0239x over previous
//
#include <hip/hip_runtime.h>

// Problem constants
#define BB 32
#define SS 512
#define DD 768
#define HH 12
#define HDIM 64
#define OL 256        // pooled query length
#define NQKV 2304     // 3*DD
#define GM (BB*SS)    // 16384 rows into the QKV GEMM

#define LOG2E 1.44269504088896f
#define NEG2 (-14426.9504089f)   // -10000 * log2(e)

typedef __bf16 bf16_t;
typedef bf16_t bf16x8 __attribute__((ext_vector_type(8)));
typedef float f32x4 __attribute__((ext_vector_type(4)));

__device__ __forceinline__ unsigned short f2bf(float f) {
  unsigned u = __float_as_uint(f);
  u = u + 0x7FFFu + ((u >> 16) & 1u);   // RNE
  return (unsigned short)(u >> 16);
}
__device__ __forceinline__ float b2f(unsigned short s) {
  return __uint_as_float(((unsigned)s) << 16);
}

// ---------------------------------------------------------------- conversions
__global__ void conv_f32_bf16(const float* __restrict__ in,
                              unsigned short* __restrict__ out, int n4) {
  int i = blockIdx.x * blockDim.x + threadIdx.x;
  if (i >= n4) return;
  float4 v = ((const float4*)in)[i];
  ushort4 o;
  o.x = f2bf(v.x); o.y = f2bf(v.y); o.z = f2bf(v.z); o.w = f2bf(v.w);
  ((ushort4*)out)[i] = o;
}

// ---------------------------------------------------------------- mask prep
// kbias is stored PRE-SCALED by log2(e): 0 for valid, -14427 for masked.
__global__ void prep_mask(const void* __restrict__ mraw,
                          float* __restrict__ kbias,
                          float* __restrict__ invn,
                          unsigned char* __restrict__ nmask,
                          float* __restrict__ out_nm) {
  int b = blockIdx.x, t = threadIdx.x;
  const unsigned char* mb = (const unsigned char*)mraw;
  bool isbyte = (mb[1] != 0);
  int idx = b * SS + t;
  int mv = isbyte ? (int)(mb[idx] != 0) : (int)(((const int*)mraw)[idx] != 0);
  kbias[idx] = mv ? 0.f : NEG2;
  if (t < OL) {
    int i0 = b * SS + 2 * t, i1 = i0 + 1;
    int m0 = isbyte ? (int)(mb[i0] != 0) : (int)(((const int*)mraw)[i0] != 0);
    int m1 = isbyte ? (int)(mb[i1] != 0) : (int)(((const int*)mraw)[i1] != 0);
    int n = m0 + m1;
    invn[b * OL + t] = (n > 0) ? 1.f / (float)n : 1.f;
    nmask[b * OL + t] = (n > 0) ? 1 : 0;
    out_nm[b * OL + t] = (n > 0) ? 1.f : 0.f;   // second tuple output
  }
}

// ---------------------------------------------------------------- QKV GEMM
// 256x128 tile, BK=64, 8 waves (4M x 2N), double-buffered LDS (96 KiB),
// counted-vmcnt pipeline (raw s_barrier, vmcnt(6) steady state),
// T2 XOR-swizzled LDS, T5 setprio, T1 XCD-chunked block swizzle.
// A LDS tile: [256][64] bf16 rows swizzled; B LDS tile: [128][64].
#define NTILES 12   // 768 / 64
__global__ __launch_bounds__(512, 2) void gemm_qkv(
    const unsigned short* __restrict__ A,
    const unsigned short* __restrict__ Bt,
    const float* __restrict__ bias,
    unsigned short* __restrict__ C) {
  __shared__ __align__(16) char smem[98304];  // 2 x (A 32K + B 16K)

  const int t = threadIdx.x;
  const int lane = t & 63;
  const int w = t >> 6;          // 0..7
  const int wm = w >> 1;         // 0..3 (M)
  const int wn = w & 1;          // 0..1 (N)
  const int fr = lane & 15, hi = lane >> 4;

  // T1: bijective XCD-chunk swizzle; 1152 blocks = 8 XCDs x 144
  // logical order m-major (n fastest): per-XCD A panel = 8 m-rows = 3.1 MB
  const int p = blockIdx.x;
  const int l = (p & 7) * 144 + (p >> 3);
  const int m0 = (l / 18) * 256;
  const int n0 = (l % 18) * 128;

  f32x4 acc[4][4] = {};

  // staging lane constants (pre-swizzled global source, m173/m201 pattern)
  const int sr8 = lane >> 3;                      // row within 8-row chunk
  const int sx8 = ((lane & 7) ^ sr8) * 8;         // xor'd element offset
  const int wq = __builtin_amdgcn_readfirstlane(w);

  const unsigned short* aSrc = A + (size_t)(m0 + wq * 8 + sr8) * DD + sx8;
  const unsigned short* bSrc = Bt + (size_t)(n0 + wq * 8 + sr8) * DD + sx8;

#define GLOAD(SRC, DST)                                                        \
  __builtin_amdgcn_global_load_lds(                                           \
      (const __attribute__((address_space(1))) unsigned int*)(SRC),           \
      (__attribute__((address_space(3))) unsigned int*)(DST), 16, 0, 0)

  // stage K-tile T into buffer (T&1): A 4 issues, B 2 issues per wave
#define STAGE(T) do {                                                          \
    char* da_ = smem + ((T) & 1) * 49152;                                      \
    char* db_ = da_ + 32768;                                                   \
    const unsigned short* as_ = aSrc + (T) * 64;                               \
    const unsigned short* bs_ = bSrc + (T) * 64;                               \
    _Pragma("unroll")                                                          \
    for (int i_ = 0; i_ < 4; ++i_)                                             \
      GLOAD(as_ + (size_t)i_ * 64 * DD, da_ + (wq * 8 + i_ * 64) * 128);       \
    _Pragma("unroll")                                                          \
    for (int i_ = 0; i_ < 2; ++i_)                                             \
      GLOAD(bs_ + (size_t)i_ * 64 * DD, db_ + (wq * 8 + i_ * 64) * 128);       \
  } while (0)

  STAGE(0);
  STAGE(1);

  for (int kt = 0; kt < NTILES; ++kt) {
    // wait: all of tile kt landed (newest 6 = tile kt+1 stay in flight)
    if (kt < NTILES - 1) {
      asm volatile("s_waitcnt vmcnt(6)" ::: "memory");
    } else {
      asm volatile("s_waitcnt vmcnt(0)" ::: "memory");
    }
    __builtin_amdgcn_sched_barrier(0);
    __builtin_amdgcn_s_barrier();
    __builtin_amdgcn_sched_barrier(0);

    const char* bA = smem + (kt & 1) * 49152;
    const char* bB = bA + 32768;

#pragma unroll
    for (int ks = 0; ks < 2; ++ks) {
      bf16x8 bfr[4], afr[4];
      const int cb = (ks * 64 + hi * 16) ^ ((fr & 7) << 4);
#pragma unroll
      for (int nf = 0; nf < 4; ++nf)
        bfr[nf] = *(const bf16x8*)(bB + (wn * 64 + nf * 16 + fr) * 128 + cb);
#pragma unroll
      for (int mf = 0; mf < 4; ++mf)
        afr[mf] = *(const bf16x8*)(bA + (wm * 64 + mf * 16 + fr) * 128 + cb);
      __builtin_amdgcn_s_setprio(1);
#pragma unroll
      for (int mf = 0; mf < 4; ++mf)
#pragma unroll
        for (int nf = 0; nf < 4; ++nf)
          acc[mf][nf] = __builtin_amdgcn_mfma_f32_16x16x32_bf16(
              afr[mf], bfr[nf], acc[mf][nf], 0, 0, 0);
      __builtin_amdgcn_s_setprio(0);
    }

    __builtin_amdgcn_sched_barrier(0);
    __builtin_amdgcn_s_barrier();
    __builtin_amdgcn_sched_barrier(0);
    if (kt + 2 < NTILES) STAGE(kt + 2);
  }
#undef STAGE
#undef GLOAD

  // epilogue: bias + bf16 store
#pragma unroll
  for (int nf = 0; nf < 4; ++nf) {
    const int gnc = n0 + wn * 64 + nf * 16 + fr;
    const float bvs = bias[gnc];
#pragma unroll
    for (int mf = 0; mf < 4; ++mf) {
      const int gmr = m0 + wm * 64 + mf * 16 + hi * 4;
#pragma unroll
      for (int j = 0; j < 4; ++j)
        C[(size_t)(gmr + j) * NQKV + gnc] = f2bf(acc[mf][nf][j] + bvs);
    }
  }
}

// ---------------------------------------------------------------- Q pooling
__global__ void pool_q(const unsigned short* __restrict__ qkv,
                       const float* __restrict__ kbias,
                       const float* __restrict__ invn,
                       unsigned short* __restrict__ qp) {
  int i = blockIdx.x * blockDim.x + threadIdx.x;
  if (i >= (BB * OL * DD) / 4) return;
  int c = (i * 4) % DD;
  int ol = (i * 4) / DD;    // b*OL + o
  int b = ol >> 8, o = ol & 255;
  int s0 = b * SS + 2 * o;
  float m0 = (kbias[s0] == 0.f) ? 1.f : 0.f;
  float m1 = (kbias[s0 + 1] == 0.f) ? 1.f : 0.f;
  float inv = invn[ol];
  const ushort4 a = *(const ushort4*)(qkv + (size_t)s0 * NQKV + c);
  const ushort4 bq = *(const ushort4*)(qkv + (size_t)(s0 + 1) * NQKV + c);
  ushort4 rr;
  rr.x = f2bf((b2f(a.x) * m0 + b2f(bq.x) * m1) * inv);
  rr.y = f2bf((b2f(a.y) * m0 + b2f(bq.y) * m1) * inv);
  rr.z = f2bf((b2f(a.z) * m0 + b2f(bq.z) * m1) * inv);
  rr.w = f2bf((b2f(a.w) * m0 + b2f(bq.w) * m1) * inv);
  *(ushort4*)(qp + (size_t)ol * DD + c) = rr;
}

// ---------------------------------------------------------------- V transpose
__global__ __launch_bounds__(256) void transp_v(const unsigned short* __restrict__ qkv,
                                                unsigned short* __restrict__ vT) {
  const int s0 = blockIdx.x * 64;
  const int h = blockIdx.y, b = blockIdx.z;
  __shared__ unsigned short tile[64][68];
  const int t = threadIdx.x;
  const int sl = t >> 4, dl = (t & 15) * 4;
#pragma unroll
  for (int i = 0; i < 4; ++i) {
    ushort4 u = *(const ushort4*)(qkv + (size_t)(b * SS + s0 + sl + i * 16) * NQKV +
                                  2 * DD + h * HDIM + dl);
    *(ushort4*)&tile[sl + i * 16][dl] = u;
  }
  __syncthreads();
  const int d2 = t >> 4, s2 = (t & 15) * 4;
#pragma unroll
  for (int i = 0; i < 4; ++i) {
    const int d = d2 + i * 16;
    ushort4 u;
    u.x = tile[s2 + 0][d]; u.y = tile[s2 + 1][d];
    u.z = tile[s2 + 2][d]; u.w = tile[s2 + 3][d];
    *(ushort4*)(vT + ((size_t)((b * HH + h) * HDIM + d)) * SS + s0 + s2) = u;
  }
}

// ---------------------------------------------------------------- attention
// slopes pre-scaled by log2(e)
__constant__ float c_slopes2[12] = {
    0.72134752f, 0.36067376f, 0.18033688f, 0.09016844f,
    0.04508422f, 0.02254211f, 0.011271055f, 0.0056355275f,
    1.02013945f, 0.51006972f, 0.25503486f, 0.12751743f};

// One wave per (b, h, 64-query tile). XCD-chunked swizzle, double-buffered
// K/V staging with counted vmcnt, fixed-max log2-domain softmax.
__global__ __launch_bounds__(64) void attn_mfma(
    const unsigned short* __restrict__ qp,    // [B][OL][768] bf16
    const unsigned short* __restrict__ qkv,   // [B*S][2304] bf16
    const unsigned short* __restrict__ vT,    // [B][H][64][512] bf16
    const float* __restrict__ kbias,          // [B][S], pre-scaled log2e
    const unsigned char* __restrict__ nmask,  // [B][OL]
    float* __restrict__ out) {                // [B][OL][768]
  __shared__ __align__(16) char smem[43008];
  const int lane = threadIdx.x;
  const int fr = lane & 15, hi = lane >> 4;

  const int p = blockIdx.x;
  const int l = (p & 7) * 192 + (p >> 3);
  const int q0 = (l & 3) * 64;
  const int bh = l >> 2;
  const int h = bh % HH, b = bh / HH;

  char* ptb = smem + 32768;
  float* kbl = (float*)(smem + 40960);

  {
    const float4* src = (const float4*)(kbias + b * SS);
    float4 v0 = src[lane];
    float4 v1 = src[lane + 64];
    ((float4*)kbl)[lane] = v0;
    ((float4*)kbl)[lane + 64] = v1;
  }

  bf16x8 qf[4][2];
#pragma unroll
  for (int m = 0; m < 4; ++m)
#pragma unroll
    for (int ks = 0; ks < 2; ++ks)
      qf[m][ks] = *(const bf16x8*)(qp + (size_t)(b * OL + q0 + m * 16 + fr) * DD +
                                   h * HDIM + ks * 32 + hi * 8);

  int qmbits = 0;
#pragma unroll
  for (int m = 0; m < 4; ++m)
#pragma unroll
    for (int j = 0; j < 4; ++j)
      if (nmask[b * OL + q0 + m * 16 + hi * 4 + j]) qmbits |= 1 << (m * 4 + j);

  const float slope2 = c_slopes2[h];
  f32x4 oacc[4][4] = {};
  float lpart[4][4] = {};

  const int srow = lane >> 3;
  const int scol = ((lane & 7) ^ srow) * 8;

#define STAGE(TILE, BUF) do {                                                  \
    char* kd_ = smem + (BUF) * 8192;                                           \
    char* vd_ = smem + 16384 + (BUF) * 8192;                                   \
    const unsigned short* ks_ = qkv + (size_t)(b * SS + (TILE) * 64 + srow) * NQKV + DD + h * HDIM + scol; \
    const unsigned short* vs_ = vT + (size_t)((b * HH + h) * HDIM + srow) * SS + (TILE) * 64 + scol;       \
    _Pragma("unroll")                                                          \
    for (int i_ = 0; i_ < 8; ++i_) {                                           \
      __builtin_amdgcn_global_load_lds(                                        \
          (const __attribute__((address_space(1))) unsigned int*)(ks_ + (size_t)i_ * 8 * NQKV), \
          (__attribute__((address_space(3))) unsigned int*)(kd_ + i_ * 1024), 16, 0, 0);        \
      __builtin_amdgcn_global_load_lds(                                        \
          (const __attribute__((address_space(1))) unsigned int*)(vs_ + (size_t)i_ * 8 * SS),   \
          (__attribute__((address_space(3))) unsigned int*)(vd_ + i_ * 1024), 16, 0, 0);        \
    }                                                                          \
  } while (0)

  STAGE(0, 0);

  for (int tile = 0; tile < 8; ++tile) {
    const int cur = tile & 1;
    const int key0 = tile * 64;
    if (tile < 7) {
      asm volatile("s_waitcnt lgkmcnt(0)" ::: "memory");
      STAGE(tile + 1, cur ^ 1);
      asm volatile("s_waitcnt vmcnt(16)" ::: "memory");
    } else {
      asm volatile("s_waitcnt vmcnt(0)" ::: "memory");
    }
    __builtin_amdgcn_sched_barrier(0);
    char* ktb = smem + cur * 8192;
    char* vtb = smem + 16384 + cur * 8192;

    // ---- QK^T
    f32x4 sacc[4][4] = {};
#pragma unroll
    for (int ks = 0; ks < 2; ++ks) {
      bf16x8 kf[4];
#pragma unroll
      for (int n = 0; n < 4; ++n) {
        const int by = ((n * 16 + fr) * 128 + (ks * 64 + hi * 16)) ^ ((fr & 7) << 4);
        kf[n] = *(const bf16x8*)(ktb + by);
      }
#pragma unroll
      for (int m = 0; m < 4; ++m)
#pragma unroll
        for (int n = 0; n < 4; ++n)
          sacc[m][n] = __builtin_amdgcn_mfma_f32_16x16x32_bf16(qf[m][ks], kf[n], sacc[m][n], 0, 0, 0);
    }

    // ---- fixed-max log2-domain softmax; P -> LDS (bf16)
    float kbv[4], keyfv[4];
#pragma unroll
    for (int n = 0; n < 4; ++n) {
      kbv[n] = kbl[key0 + n * 16 + fr];
      keyfv[n] = (float)(key0 + n * 16 + fr);
    }
#pragma unroll
    for (int m = 0; m < 4; ++m) {
#pragma unroll
      for (int j = 0; j < 4; ++j) {
        const bool qm = (qmbits >> (m * 4 + j)) & 1;
        const float qvf = (float)(q0 + m * 16 + hi * 4 + j);
        float lp = lpart[m][j];
#pragma unroll
        for (int n = 0; n < 4; ++n) {
          const float biasv = qm ? kbv[n] : 0.f;
          const float rel = fabsf(keyfv[n] - qvf);
          float tv = fmaf(sacc[m][n][j], 0.18033688011f, biasv);
          tv = fmaf(rel, -slope2, tv);
          float pe;
          asm("v_exp_f32 %0, %1" : "=v"(pe) : "v"(tv));
          lp += pe;
          const int by = ((m * 16 + hi * 4 + j) * 128 + (n * 16 + fr) * 2) ^
                         (((hi * 4 + j) & 7) << 4);
          *(unsigned short*)(ptb + by) = f2bf(pe);
        }
        lpart[m][j] = lp;
      }
    }
    asm volatile("s_waitcnt lgkmcnt(0)" ::: "memory");
    __builtin_amdgcn_sched_barrier(0);

    // ---- PV
#pragma unroll
    for (int ks = 0; ks < 2; ++ks) {
      bf16x8 pf[4], vf[4];
#pragma unroll
      for (int m = 0; m < 4; ++m) {
        const int by = ((m * 16 + fr) * 128 + (ks * 64 + hi * 16)) ^ ((fr & 7) << 4);
        pf[m] = *(const bf16x8*)(ptb + by);
      }
#pragma unroll
      for (int nd = 0; nd < 4; ++nd) {
        const int by = ((nd * 16 + fr) * 128 + (ks * 64 + hi * 16)) ^ ((fr & 7) << 4);
        vf[nd] = *(const bf16x8*)(vtb + by);
      }
#pragma unroll
      for (int m = 0; m < 4; ++m)
#pragma unroll
        for (int nd = 0; nd < 4; ++nd)
          oacc[m][nd] = __builtin_amdgcn_mfma_f32_16x16x32_bf16(pf[m], vf[nd], oacc[m][nd], 0, 0, 0);
    }
  }
#undef STAGE

  // ---- epilogue: reduce l, normalize, transpose via LDS, coalesced store
  float* ot = (float*)smem;   // 64 x 68 f32 tile (17408 B)
#pragma unroll
  for (int m = 0; m < 4; ++m)
#pragma unroll
    for (int j = 0; j < 4; ++j) {
      float lv = lpart[m][j];
      lv += __shfl_xor(lv, 1, 64);
      lv += __shfl_xor(lv, 2, 64);
      lv += __shfl_xor(lv, 4, 64);
      lv += __shfl_xor(lv, 8, 64);
      const float rl = 1.f / lv;
      const int row = m * 16 + hi * 4 + j;
#pragma unroll
      for (int nd = 0; nd < 4; ++nd)
        ot[row * 68 + nd * 16 + fr] = oacc[m][nd][j] * rl;
    }
  asm volatile("s_waitcnt lgkmcnt(0)" ::: "memory");
  __builtin_amdgcn_sched_barrier(0);
#pragma unroll
  for (int i = 0; i < 16; ++i) {
    const int idx = i * 64 + lane;       // float4 index
    const int row = idx >> 4, c4 = idx & 15;
    const float4 v = *(const float4*)&ot[row * 68 + c4 * 4];
    *(float4*)(out + (size_t)(b * OL + q0 + row) * DD + h * HDIM + c4 * 4) = v;
  }
}

// ---------------------------------------------------------------- launch
extern "C" void kernel_launch(void* const* d_in, const int* in_sizes, int n_in,
                              void* d_out, int out_size, void* d_ws, size_t ws_size,
                              hipStream_t stream) {
  const float* hidden = (const float*)d_in[0];
  const void* maskraw = d_in[1];
  const float* W = (const float*)d_in[2];
  const float* bias = (const float*)d_in[3];
  float* out = (float*)d_out;

  char* ws = (char*)d_ws;
  unsigned short* Abf = (unsigned short*)(ws);                 // 25,165,824 B
  unsigned short* vT  = (unsigned short*)(ws);                 // reuses Abf after GEMM
  unsigned short* Btb = (unsigned short*)(ws + 25165824);      //  3,538,944 B
  unsigned short* qkv = (unsigned short*)(ws + 28704768);      // 75,497,472 B
  unsigned short* qp  = (unsigned short*)(ws + 104202240);     // 12,582,912 B
  float* kbias        = (float*)(ws + 116785152);              //     65,536 B
  float* invn         = (float*)(ws + 116850688);              //     32,768 B
  unsigned char* nmask = (unsigned char*)(ws + 116883456);     //      8,192 B

  float* out_nm = out + (size_t)BB * OL * DD;  // new_mask part of d_out

  conv_f32_bf16<<<(GM * DD / 4 + 255) / 256, 256, 0, stream>>>(hidden, Abf, GM * DD / 4);
  conv_f32_bf16<<<(NQKV * DD / 4 + 255) / 256, 256, 0, stream>>>(W, Btb, NQKV * DD / 4);
  prep_mask<<<BB, SS, 0, stream>>>(maskraw, kbias, invn, nmask, out_nm);
  gemm_qkv<<<1152, 512, 0, stream>>>(Abf, Btb, bias, qkv);
  pool_q<<<(BB * OL * DD / 4 + 255) / 256, 256, 0, stream>>>(qkv, kbias, invn, qp);
  transp_v<<<dim3(SS / 64, HH, BB), 256, 0, stream>>>(qkv, vT);
  attn_mfma<<<1536, 64, 0, stream>>>(qp, qkv, vT, kbias, nmask, out);
}

// Round 5
// 130.848 us; speedup vs baseline: 4.6838x; 1.2397x over previous
//
#include <hip/hip_runtime.h>

// Problem constants
#define BB 32
#define SS 512
#define DD 768
#define HH 12
#define HDIM 64
#define OL 256        // pooled query length
#define NQKV 2304     // 3*DD
#define GM (BB*SS)    // 16384 rows into the QKV GEMM

#define NEG2 (-14426.9504089f)   // -10000 * log2(e)

typedef __bf16 bf16_t;
typedef bf16_t bf16x8 __attribute__((ext_vector_type(8)));
typedef float f32x4 __attribute__((ext_vector_type(4)));
typedef unsigned short u16x8 __attribute__((ext_vector_type(8)));

__device__ __forceinline__ unsigned short f2bf(float f) {
  unsigned u = __float_as_uint(f);
  u = u + 0x7FFFu + ((u >> 16) & 1u);   // RNE
  return (unsigned short)(u >> 16);
}
__device__ __forceinline__ float b2f(unsigned short s) {
  return __uint_as_float(((unsigned)s) << 16);
}

// ---------------------------------------------------------------- conversions
__global__ void conv_f32_bf16(const float* __restrict__ in,
                              unsigned short* __restrict__ out, int n4) {
  int i = blockIdx.x * blockDim.x + threadIdx.x;
  if (i >= n4) return;
  float4 v = ((const float4*)in)[i];
  ushort4 o;
  o.x = f2bf(v.x); o.y = f2bf(v.y); o.z = f2bf(v.z); o.w = f2bf(v.w);
  ((ushort4*)out)[i] = o;
}

// ---------------------------------------------------------------- mask prep
// kbias pre-scaled by log2(e): 0 valid, -14427 masked.
__global__ void prep_mask(const void* __restrict__ mraw,
                          float* __restrict__ kbias,
                          float* __restrict__ invn,
                          unsigned char* __restrict__ nmask,
                          float* __restrict__ out_nm) {
  int b = blockIdx.x, t = threadIdx.x;
  const unsigned char* mb = (const unsigned char*)mraw;
  bool isbyte = (mb[1] != 0);
  int idx = b * SS + t;
  int mv = isbyte ? (int)(mb[idx] != 0) : (int)(((const int*)mraw)[idx] != 0);
  kbias[idx] = mv ? 0.f : NEG2;
  if (t < OL) {
    int i0 = b * SS + 2 * t, i1 = i0 + 1;
    int m0 = isbyte ? (int)(mb[i0] != 0) : (int)(((const int*)mraw)[i0] != 0);
    int m1 = isbyte ? (int)(mb[i1] != 0) : (int)(((const int*)mraw)[i1] != 0);
    int n = m0 + m1;
    invn[b * OL + t] = (n > 0) ? 1.f / (float)n : 1.f;
    nmask[b * OL + t] = (n > 0) ? 1 : 0;
    out_nm[b * OL + t] = (n > 0) ? 1.f : 0.f;   // second tuple output
  }
}

// ---------------------------------------------------------------- QKV GEMM
// 128x128 tile, BK=64, 4 waves (2M x 2N), dbuf LDS 64 KiB -> 2 blocks/CU.
// Counted-vmcnt pipeline, T2 XOR-swizzle, T5 setprio, T1 XCD swizzle.
// Fused epilogues: n-blocks 0-5 -> pooled qp; 6-11 -> Kbuf; 12-17 -> vT.
#define NT 12   // 768 / 64
__global__ __launch_bounds__(256, 2) void gemm_qkv(
    const unsigned short* __restrict__ A,
    const unsigned short* __restrict__ Bt,
    const float* __restrict__ bias,
    unsigned short* __restrict__ Kbuf,   // [B*S][768]
    unsigned short* __restrict__ qp,     // [B*OL][768]
    unsigned short* __restrict__ vT,     // [B][H][64][512]
    const float* __restrict__ kbias,
    const float* __restrict__ invn) {
  __shared__ __align__(16) char smem[65536];  // 2 x (A 16K + B 16K)

  const int t = threadIdx.x;
  const int lane = t & 63;
  const int w = t >> 6;          // 0..3
  const int wm = w >> 1, wn = w & 1;
  const int fr = lane & 15, hi = lane >> 4;

  // T1: bijective XCD-chunk swizzle; 2304 blocks = 8 XCDs x 288 (m-major)
  const int p = blockIdx.x;
  const int l = (p & 7) * 288 + (p >> 3);
  const int m0 = (l / 18) * 128;
  const int n0 = (l % 18) * 128;
  const int b = m0 >> 9;         // batch (128 | 512)
  const int s0 = m0 & 511;       // seq offset of row 0

  f32x4 acc[4][4] = {};

  const int sr8 = lane >> 3;                      // 0..7
  const int sx8 = ((lane & 7) ^ sr8) * 8;         // pre-swizzled src col
  const int wq = __builtin_amdgcn_readfirstlane(w);
  const unsigned short* aSrc = A + (size_t)(m0 + wq * 32 + sr8) * DD + sx8;
  const unsigned short* bSrc = Bt + (size_t)(n0 + wq * 32 + sr8) * DD + sx8;

#define GLOAD(SRC, DST)                                                        \
  __builtin_amdgcn_global_load_lds(                                           \
      (const __attribute__((address_space(1))) unsigned int*)(SRC),           \
      (__attribute__((address_space(3))) unsigned int*)(DST), 16, 0, 0)

  // 8 loads per wave per tile: 4 A-row-chunks + 4 B-row-chunks
#define STAGE(T) do {                                                          \
    char* da_ = smem + ((T) & 1) * 32768;                                      \
    char* db_ = da_ + 16384;                                                   \
    const unsigned short* as_ = aSrc + (T) * 64;                               \
    const unsigned short* bs_ = bSrc + (T) * 64;                               \
    _Pragma("unroll")                                                          \
    for (int i_ = 0; i_ < 4; ++i_) {                                           \
      GLOAD(as_ + (size_t)i_ * 8 * DD, da_ + (wq * 32 + i_ * 8) * 128);        \
      GLOAD(bs_ + (size_t)i_ * 8 * DD, db_ + (wq * 32 + i_ * 8) * 128);        \
    }                                                                          \
  } while (0)

  STAGE(0);
  STAGE(1);

  const int cb0 = (hi * 16) ^ ((fr & 7) << 4);
  const int cb1 = (64 + hi * 16) ^ ((fr & 7) << 4);

  for (int kt = 0; kt < NT; ++kt) {
    if (kt < NT - 1) {
      asm volatile("s_waitcnt vmcnt(8)" ::: "memory");
    } else {
      asm volatile("s_waitcnt vmcnt(0)" ::: "memory");
    }
    __builtin_amdgcn_sched_barrier(0);
    __builtin_amdgcn_s_barrier();
    __builtin_amdgcn_sched_barrier(0);

    const char* bA = smem + (kt & 1) * 32768;
    const char* bB = bA + 16384;

    bf16x8 a0[4], b0[4], a1[4], b1[4];
#pragma unroll
    for (int f = 0; f < 4; ++f) {
      a0[f] = *(const bf16x8*)(bA + (wm * 64 + f * 16 + fr) * 128 + cb0);
      b0[f] = *(const bf16x8*)(bB + (wn * 64 + f * 16 + fr) * 128 + cb0);
    }
    __builtin_amdgcn_sched_barrier(0);
#pragma unroll
    for (int f = 0; f < 4; ++f) {
      a1[f] = *(const bf16x8*)(bA + (wm * 64 + f * 16 + fr) * 128 + cb1);
      b1[f] = *(const bf16x8*)(bB + (wn * 64 + f * 16 + fr) * 128 + cb1);
    }
    asm volatile("s_waitcnt lgkmcnt(8)" ::: "memory");
    __builtin_amdgcn_sched_barrier(0);
    __builtin_amdgcn_s_setprio(1);
#pragma unroll
    for (int mf = 0; mf < 4; ++mf)
#pragma unroll
      for (int nf = 0; nf < 4; ++nf)
        acc[mf][nf] = __builtin_amdgcn_mfma_f32_16x16x32_bf16(
            a0[mf], b0[nf], acc[mf][nf], 0, 0, 0);
    __builtin_amdgcn_s_setprio(0);
    asm volatile("s_waitcnt lgkmcnt(0)" ::: "memory");
    __builtin_amdgcn_sched_barrier(0);
    __builtin_amdgcn_s_barrier();     // all waves done reading this buffer
    __builtin_amdgcn_sched_barrier(0);
    if (kt + 2 < NT) STAGE(kt + 2);   // writes this parity — now safe
    __builtin_amdgcn_sched_barrier(0);
    __builtin_amdgcn_s_setprio(1);
#pragma unroll
    for (int mf = 0; mf < 4; ++mf)
#pragma unroll
      for (int nf = 0; nf < 4; ++nf)
        acc[mf][nf] = __builtin_amdgcn_mfma_f32_16x16x32_bf16(
            a1[mf], b1[nf], acc[mf][nf], 0, 0, 0);
    __builtin_amdgcn_s_setprio(0);
  }
#undef STAGE
#undef GLOAD

  // ---------------- fused epilogues
  const int ntype = n0 / 768;   // 0=Q(pool), 1=K, 2=V(transpose)
  if (ntype == 1) {
#pragma unroll
    for (int nf = 0; nf < 4; ++nf) {
      const int nc = wn * 64 + nf * 16 + fr;
      const float bvs = bias[n0 + nc];
      const int gnc = n0 - 768 + nc;
#pragma unroll
      for (int mf = 0; mf < 4; ++mf) {
        const int gmr = m0 + wm * 64 + mf * 16 + hi * 4;
#pragma unroll
        for (int j = 0; j < 4; ++j)
          Kbuf[(size_t)(gmr + j) * 768 + gnc] = f2bf(acc[mf][nf][j] + bvs);
      }
    }
  } else if (ntype == 0) {
#pragma unroll
    for (int mf = 0; mf < 4; ++mf) {
      const int sl = s0 + wm * 64 + mf * 16 + hi * 4;   // seq of j=0
      const float4 km = *(const float4*)&kbias[b * SS + sl];
      const float2 iv = *(const float2*)&invn[b * OL + (sl >> 1)];
      const float w0 = (km.x == 0.f) ? iv.x : 0.f;
      const float w1 = (km.y == 0.f) ? iv.x : 0.f;
      const float w2 = (km.z == 0.f) ? iv.y : 0.f;
      const float w3 = (km.w == 0.f) ? iv.y : 0.f;
      const int o0 = b * OL + (sl >> 1);
#pragma unroll
      for (int nf = 0; nf < 4; ++nf) {
        const int gnc = n0 + wn * 64 + nf * 16 + fr;
        const float bvs = bias[gnc];
        const f32x4 a = acc[mf][nf];
        qp[(size_t)o0 * DD + gnc] = f2bf((a[0] + bvs) * w0 + (a[1] + bvs) * w1);
        qp[(size_t)(o0 + 1) * DD + gnc] = f2bf((a[2] + bvs) * w2 + (a[3] + bvs) * w3);
      }
    }
  } else {
    // V: bias + bf16 into LDS [128 n][136 m], then transposed coalesced store
    unsigned short* lt = (unsigned short*)smem;
#pragma unroll
    for (int nf = 0; nf < 4; ++nf) {
      const int nl = wn * 64 + nf * 16 + fr;
      const float bvs = bias[n0 + nl];
#pragma unroll
      for (int mf = 0; mf < 4; ++mf) {
        const int mb = wm * 64 + mf * 16 + hi * 4;
        ushort4 pk;
        pk.x = f2bf(acc[mf][nf][0] + bvs);
        pk.y = f2bf(acc[mf][nf][1] + bvs);
        pk.z = f2bf(acc[mf][nf][2] + bvs);
        pk.w = f2bf(acc[mf][nf][3] + bvs);
        *(ushort4*)&lt[nl * 136 + mb] = pk;
      }
    }
    __syncthreads();
#pragma unroll
    for (int i = 0; i < 8; ++i) {
      const int row = i * 16 + (t >> 4);
      const int ch = t & 15;
      const u16x8 v = *(const u16x8*)&lt[row * 136 + ch * 8];
      const int n = n0 - 1536 + row;
      const int h2 = n >> 6, d2 = n & 63;
      *(u16x8*)(vT + ((size_t)((b * HH + h2) * HDIM + d2)) * 512 + s0 + ch * 8) = v;
    }
  }
}

// ---------------------------------------------------------------- attention
// slopes pre-scaled by log2(e)
__constant__ float c_slopes2[12] = {
    0.72134752f, 0.36067376f, 0.18033688f, 0.09016844f,
    0.04508422f, 0.02254211f, 0.011271055f, 0.0056355275f,
    1.02013945f, 0.51006972f, 0.25503486f, 0.12751743f};

// One wave per (b, h, 64-query tile). XCD-chunked swizzle, double-buffered
// K/V staging with counted vmcnt, fixed-max log2-domain softmax.
__global__ __launch_bounds__(64) void attn_mfma(
    const unsigned short* __restrict__ qp,    // [B][OL][768] bf16
    const unsigned short* __restrict__ Kb,    // [B*S][768] bf16
    const unsigned short* __restrict__ vT,    // [B][H][64][512] bf16
    const float* __restrict__ kbias,          // [B][S], pre-scaled log2e
    const unsigned char* __restrict__ nmask,  // [B][OL]
    float* __restrict__ out) {                // [B][OL][768]
  __shared__ __align__(16) char smem[43008];
  const int lane = threadIdx.x;
  const int fr = lane & 15, hi = lane >> 4;

  const int p = blockIdx.x;
  const int l = (p & 7) * 192 + (p >> 3);
  const int q0 = (l & 3) * 64;
  const int bh = l >> 2;
  const int h = bh % HH, b = bh / HH;

  char* ptb = smem + 32768;
  float* kbl = (float*)(smem + 40960);

  {
    const float4* src = (const float4*)(kbias + b * SS);
    float4 v0 = src[lane];
    float4 v1 = src[lane + 64];
    ((float4*)kbl)[lane] = v0;
    ((float4*)kbl)[lane + 64] = v1;
  }

  bf16x8 qf[4][2];
#pragma unroll
  for (int m = 0; m < 4; ++m)
#pragma unroll
    for (int ks = 0; ks < 2; ++ks)
      qf[m][ks] = *(const bf16x8*)(qp + (size_t)(b * OL + q0 + m * 16 + fr) * DD +
                                   h * HDIM + ks * 32 + hi * 8);

  int qmbits = 0;
#pragma unroll
  for (int m = 0; m < 4; ++m)
#pragma unroll
    for (int j = 0; j < 4; ++j)
      if (nmask[b * OL + q0 + m * 16 + hi * 4 + j]) qmbits |= 1 << (m * 4 + j);

  const float slope2 = c_slopes2[h];
  f32x4 oacc[4][4] = {};
  float lpart[4][4] = {};

  const int srow = lane >> 3;
  const int scol = ((lane & 7) ^ srow) * 8;

#define STAGE(TILE, BUF) do {                                                  \
    char* kd_ = smem + (BUF) * 8192;                                           \
    char* vd_ = smem + 16384 + (BUF) * 8192;                                   \
    const unsigned short* ks_ = Kb + (size_t)(b * SS + (TILE) * 64 + srow) * 768 + h * HDIM + scol; \
    const unsigned short* vs_ = vT + (size_t)((b * HH + h) * HDIM + srow) * SS + (TILE) * 64 + scol;       \
    _Pragma("unroll")                                                          \
    for (int i_ = 0; i_ < 8; ++i_) {                                           \
      __builtin_amdgcn_global_load_lds(                                        \
          (const __attribute__((address_space(1))) unsigned int*)(ks_ + (size_t)i_ * 8 * 768), \
          (__attribute__((address_space(3))) unsigned int*)(kd_ + i_ * 1024), 16, 0, 0);        \
      __builtin_amdgcn_global_load_lds(                                        \
          (const __attribute__((address_space(1))) unsigned int*)(vs_ + (size_t)i_ * 8 * SS),   \
          (__attribute__((address_space(3))) unsigned int*)(vd_ + i_ * 1024), 16, 0, 0);        \
    }                                                                          \
  } while (0)

  STAGE(0, 0);

  for (int tile = 0; tile < 8; ++tile) {
    const int cur = tile & 1;
    const int key0 = tile * 64;
    if (tile < 7) {
      asm volatile("s_waitcnt lgkmcnt(0)" ::: "memory");
      STAGE(tile + 1, cur ^ 1);
      asm volatile("s_waitcnt vmcnt(16)" ::: "memory");
    } else {
      asm volatile("s_waitcnt vmcnt(0)" ::: "memory");
    }
    __builtin_amdgcn_sched_barrier(0);
    char* ktb = smem + cur * 8192;
    char* vtb = smem + 16384 + cur * 8192;

    // ---- QK^T
    f32x4 sacc[4][4] = {};
#pragma unroll
    for (int ks = 0; ks < 2; ++ks) {
      bf16x8 kf[4];
#pragma unroll
      for (int n = 0; n < 4; ++n) {
        const int by = ((n * 16 + fr) * 128 + (ks * 64 + hi * 16)) ^ ((fr & 7) << 4);
        kf[n] = *(const bf16x8*)(ktb + by);
      }
#pragma unroll
      for (int m = 0; m < 4; ++m)
#pragma unroll
        for (int n = 0; n < 4; ++n)
          sacc[m][n] = __builtin_amdgcn_mfma_f32_16x16x32_bf16(qf[m][ks], kf[n], sacc[m][n], 0, 0, 0);
    }

    // ---- fixed-max log2-domain softmax; P -> LDS (bf16)
    float kbv[4], keyfv[4];
#pragma unroll
    for (int n = 0; n < 4; ++n) {
      kbv[n] = kbl[key0 + n * 16 + fr];
      keyfv[n] = (float)(key0 + n * 16 + fr);
    }
#pragma unroll
    for (int m = 0; m < 4; ++m) {
#pragma unroll
      for (int j = 0; j < 4; ++j) {
        const bool qm = (qmbits >> (m * 4 + j)) & 1;
        const float qvf = (float)(q0 + m * 16 + hi * 4 + j);
        float lp = lpart[m][j];
#pragma unroll
        for (int n = 0; n < 4; ++n) {
          const float biasv = qm ? kbv[n] : 0.f;
          const float rel = fabsf(keyfv[n] - qvf);
          float tv = fmaf(sacc[m][n][j], 0.18033688011f, biasv);
          tv = fmaf(rel, -slope2, tv);
          float pe;
          asm("v_exp_f32 %0, %1" : "=v"(pe) : "v"(tv));
          lp += pe;
          const int by = ((m * 16 + hi * 4 + j) * 128 + (n * 16 + fr) * 2) ^
                         (((hi * 4 + j) & 7) << 4);
          *(unsigned short*)(ptb + by) = f2bf(pe);
        }
        lpart[m][j] = lp;
      }
    }
    asm volatile("s_waitcnt lgkmcnt(0)" ::: "memory");
    __builtin_amdgcn_sched_barrier(0);

    // ---- PV
#pragma unroll
    for (int ks = 0; ks < 2; ++ks) {
      bf16x8 pf[4], vf[4];
#pragma unroll
      for (int m = 0; m < 4; ++m) {
        const int by = ((m * 16 + fr) * 128 + (ks * 64 + hi * 16)) ^ ((fr & 7) << 4);
        pf[m] = *(const bf16x8*)(ptb + by);
      }
#pragma unroll
      for (int nd = 0; nd < 4; ++nd) {
        const int by = ((nd * 16 + fr) * 128 + (ks * 64 + hi * 16)) ^ ((fr & 7) << 4);
        vf[nd] = *(const bf16x8*)(vtb + by);
      }
#pragma unroll
      for (int m = 0; m < 4; ++m)
#pragma unroll
        for (int nd = 0; nd < 4; ++nd)
          oacc[m][nd] = __builtin_amdgcn_mfma_f32_16x16x32_bf16(pf[m], vf[nd], oacc[m][nd], 0, 0, 0);
    }
  }
#undef STAGE

  // ---- epilogue: reduce l, normalize, transpose via LDS, coalesced store
  float* ot = (float*)smem;   // 64 x 68 f32 tile (17408 B)
#pragma unroll
  for (int m = 0; m < 4; ++m)
#pragma unroll
    for (int j = 0; j < 4; ++j) {
      float lv = lpart[m][j];
      lv += __shfl_xor(lv, 1, 64);
      lv += __shfl_xor(lv, 2, 64);
      lv += __shfl_xor(lv, 4, 64);
      lv += __shfl_xor(lv, 8, 64);
      const float rl = 1.f / lv;
      const int row = m * 16 + hi * 4 + j;
#pragma unroll
      for (int nd = 0; nd < 4; ++nd)
        ot[row * 68 + nd * 16 + fr] = oacc[m][nd][j] * rl;
    }
  asm volatile("s_waitcnt lgkmcnt(0)" ::: "memory");
  __builtin_amdgcn_sched_barrier(0);
#pragma unroll
  for (int i = 0; i < 16; ++i) {
    const int idx = i * 64 + lane;       // float4 index
    const int row = idx >> 4, c4 = idx & 15;
    const float4 v = *(const float4*)&ot[row * 68 + c4 * 4];
    *(float4*)(out + (size_t)(b * OL + q0 + row) * DD + h * HDIM + c4 * 4) = v;
  }
}

// ---------------------------------------------------------------- launch
extern "C" void kernel_launch(void* const* d_in, const int* in_sizes, int n_in,
                              void* d_out, int out_size, void* d_ws, size_t ws_size,
                              hipStream_t stream) {
  const float* hidden = (const float*)d_in[0];
  const void* maskraw = d_in[1];
  const float* W = (const float*)d_in[2];
  const float* bias = (const float*)d_in[3];
  float* out = (float*)d_out;

  char* ws = (char*)d_ws;
  unsigned short* Abf  = (unsigned short*)(ws);                 // 25,165,824 B
  unsigned short* Btb  = (unsigned short*)(ws + 25165824);      //  3,538,944 B
  unsigned short* Kbuf = (unsigned short*)(ws + 28704768);      // 25,165,824 B
  unsigned short* vT   = (unsigned short*)(ws + 53870592);      // 25,165,824 B
  unsigned short* qp   = (unsigned short*)(ws + 79036416);      // 12,582,912 B
  float* kbias         = (float*)(ws + 91619328);               //     65,536 B
  float* invn          = (float*)(ws + 91684864);               //     32,768 B
  unsigned char* nmask = (unsigned char*)(ws + 91717632);       //      8,192 B

  float* out_nm = out + (size_t)BB * OL * DD;  // new_mask part of d_out

  conv_f32_bf16<<<(GM * DD / 4 + 255) / 256, 256, 0, stream>>>(hidden, Abf, GM * DD / 4);
  conv_f32_bf16<<<(NQKV * DD / 4 + 255) / 256, 256, 0, stream>>>(W, Btb, NQKV * DD / 4);
  prep_mask<<<BB, SS, 0, stream>>>(maskraw, kbias, invn, nmask, out_nm);
  gemm_qkv<<<2304, 256, 0, stream>>>(Abf, Btb, bias, Kbuf, qp, vT, kbias, invn);
  attn_mfma<<<1536, 64, 0, stream>>>(qp, Kbuf, vT, kbias, nmask, out);
}